// Round 13
// baseline (60.680 us; speedup 1.0000x reference)
//
#include <hip/hip_runtime.h>
#include <math.h>

// NoisyTopkRouter: B=4 S=4096 D=2048 E=16 K=2, TEMPERATURE=1. rows = 16384.
// out layout (fp32): router_output [16384*16] | indices-as-float [16384*2] | aux_loss [1]
// Round 13: split-K, 3 kernels.
//  k1 gemv: grid 256 rowtiles x NS dslices, 256 thr (4 waves x (512/NS)-d).
//     R=8 rows x C=4 experts/thread (r9's best-ratio dataflow), W ping-pong
//     regs, x dbuf LDS [2][64][16] (r9-verified swizzle), no main-loop
//     barriers. 36KB LDS -> 4-block budget target -> 128 VGPR >= ~95 demand;
//     grid 256*NS -> NS blocks/CU -> NS*4 waves/CU. dslice = bid%NS: with
//     8-XCD round-robin each XCD sees ONE dslice -> W slice L2-resident.
//  k2 epilogue: 256 blocks x 64 lanes, lane=row: sum NS partials, softplus/
//     top2/softmax in regs, butterfly block sums.
//  k3 aux. Host picks NS from ws_size (8.4MB needed for NS=4).

#define DDIM 2048
#define NEXP 16
#define IDX_OFF 262144
#define AUX_OFF 294912

#define FMA_ROW(WPA, GG, i) { \
    const float4 xv = *(const float4*)(xb + (rg + 8 * (i)) * 16 + (((GG) ^ sw) << 2)); \
    acc[i].x = fmaf(xv.w, WPA[3].x, fmaf(xv.z, WPA[2].x, fmaf(xv.y, WPA[1].x, fmaf(xv.x, WPA[0].x, acc[i].x)))); \
    acc[i].y = fmaf(xv.w, WPA[3].y, fmaf(xv.z, WPA[2].y, fmaf(xv.y, WPA[1].y, fmaf(xv.x, WPA[0].y, acc[i].y)))); \
    acc[i].z = fmaf(xv.w, WPA[3].z, fmaf(xv.z, WPA[2].z, fmaf(xv.y, WPA[1].z, fmaf(xv.x, WPA[0].z, acc[i].z)))); \
    acc[i].w = fmaf(xv.w, WPA[3].w, fmaf(xv.z, WPA[2].w, fmaf(xv.y, WPA[1].w, fmaf(xv.x, WPA[0].w, acc[i].w)))); }

template<int NS>
__global__ __launch_bounds__(256) void gemv_k(
    const float* __restrict__ x, const float* __restrict__ wr,
    const float* __restrict__ wn, float* __restrict__ pbase) {
  constexpr int WAVE_DS = 512 / NS;     // d per wave
  constexpr int NCHNK = WAVE_DS / 16;   // 16-d chunks
  __shared__ float smem[9216];          // 36KB: x dbuf [4][2][64][16] / reduce [4][64][32]

  const int tid  = threadIdx.x;
  const int wave = tid >> 6;
  const int lane = tid & 63;
  const int rg   = lane >> 3;           // 0..7 -> rows {rg + 8i}, i=0..7
  const int q    = lane & 7;            // q<4: route experts 4q..; q>=4: noise
  const int sw   = rg >> 1;             // read-side LDS quad swizzle
  const int rowtile = blockIdx.x / NS;
  const int dslice  = blockIdx.x % NS;
  const int row_base = rowtile * 64;
  const int d_base   = dslice * (DDIM / NS) + wave * WAVE_DS;

  float* xregion = smem + wave * 2048;  // [2][64][16]

  // staging: lane -> (srow = lane>>2, quad = lane&3); rows srow+16t, t=0..3
  const int srow  = lane >> 2;
  const int squad = lane & 3;
  const float* xsrc = x + (size_t)(row_base + srow) * DDIM + d_base + squad * 4;
  const int lwoff = srow * 16 + ((squad ^ ((srow >> 1) & 3)) << 2);  // key invariant under row+16

  const float* wbase = (q < 4 ? wr : wn) + (size_t)d_base * NEXP + (q & 3) * 4;

  float4 acc[8];
  #pragma unroll
  for (int i = 0; i < 8; ++i) acc[i] = make_float4(0.f, 0.f, 0.f, 0.f);

  float4 wp0[4], wp1[4];
  float4 xp[4];

  // prologue: W groups 0,1 + x chunk 0 -> buffer 0
  #pragma unroll
  for (int j = 0; j < 4; ++j) wp0[j] = *(const float4*)(wbase + j * NEXP);
  #pragma unroll
  for (int j = 0; j < 4; ++j) wp1[j] = *(const float4*)(wbase + 64 + j * NEXP);
  #pragma unroll
  for (int t = 0; t < 4; ++t) xp[t] = *(const float4*)(xsrc + (size_t)t * 16 * DDIM);
  #pragma unroll
  for (int t = 0; t < 4; ++t) *(float4*)(xregion + lwoff + t * 256) = xp[t];

  for (int k = 0; k < NCHNK; ++k) {
    const float* xb = xregion + (k & 1) * 1024;
    if (k + 1 < NCHNK) {
      #pragma unroll
      for (int t = 0; t < 4; ++t)
        xp[t] = *(const float4*)(xsrc + (size_t)t * 16 * DDIM + (k + 1) * 16);
    }
    // gg=0: consume wp0, refill <- group 4k+2 (<= 4*NCHNK-2, unguarded)
    #pragma unroll
    for (int i = 0; i < 8; ++i) FMA_ROW(wp0, 0, i);
    { const float* wl = wbase + (size_t)(4 * k + 2) * 64;
      #pragma unroll
      for (int j = 0; j < 4; ++j) wp0[j] = *(const float4*)(wl + j * NEXP); }
    // gg=1: consume wp1, refill <- group 4k+3 (<= 4*NCHNK-1, unguarded)
    #pragma unroll
    for (int i = 0; i < 8; ++i) FMA_ROW(wp1, 1, i);
    { const float* wl = wbase + (size_t)(4 * k + 3) * 64;
      #pragma unroll
      for (int j = 0; j < 4; ++j) wp1[j] = *(const float4*)(wl + j * NEXP); }
    // gg=2: consume wp0, refill <- group 4k+4 (guarded)
    #pragma unroll
    for (int i = 0; i < 8; ++i) FMA_ROW(wp0, 2, i);
    if (k + 1 < NCHNK) {
      const float* wl = wbase + (size_t)(4 * k + 4) * 64;
      #pragma unroll
      for (int j = 0; j < 4; ++j) wp0[j] = *(const float4*)(wl + j * NEXP);
    }
    // gg=3: consume wp1, refill <- group 4k+5; write x chunk k+1
    #pragma unroll
    for (int i = 0; i < 8; ++i) FMA_ROW(wp1, 3, i);
    if (k + 1 < NCHNK) {
      const float* wl = wbase + (size_t)(4 * k + 5) * 64;
      #pragma unroll
      for (int j = 0; j < 4; ++j) wp1[j] = *(const float4*)(wl + j * NEXP);
      float* xw = xregion + ((k + 1) & 1) * 1024;
      #pragma unroll
      for (int t = 0; t < 4; ++t) *(float4*)(xw + lwoff + t * 256) = xp[t];
    }
  }

  // dump acc into own wave region [64][32], swizzled quad q^rg (private: no pre-sync)
  {
    float* pr = xregion;
    const int psw = (q ^ rg) << 2;
    #pragma unroll
    for (int i = 0; i < 8; ++i)
      *(float4*)(pr + (rg + 8 * i) * 32 + psw) = acc[i];
  }
  __syncthreads();

  // combine 4 wave regions -> partial [64][32], coalesced store
  float* pws = pbase + (size_t)(dslice * 256 + rowtile) * 2048;
  #pragma unroll
  for (int u = 0; u < 2; ++u) {
    const int f   = tid * 2 + u;          // 0..511 float4 slots
    const int row = f >> 3;
    const int g   = f & 7;
    const int off = row * 32 + ((g ^ (row & 7)) << 2);
    float4 a0 = *(const float4*)(smem + 0 * 2048 + off);
    float4 a1 = *(const float4*)(smem + 1 * 2048 + off);
    float4 a2 = *(const float4*)(smem + 2 * 2048 + off);
    float4 a3 = *(const float4*)(smem + 3 * 2048 + off);
    float4 s = make_float4((a0.x + a1.x) + (a2.x + a3.x),
                           (a0.y + a1.y) + (a2.y + a3.y),
                           (a0.z + a1.z) + (a2.z + a3.z),
                           (a0.w + a1.w) + (a2.w + a3.w));
    *(float4*)(pws + row * 32 + g * 4) = s;
  }
}

template<int NS>
__global__ __launch_bounds__(64) void epi_k(
    const float* __restrict__ pbase, const float* __restrict__ br,
    const float* __restrict__ bn, const float* __restrict__ eps,
    float* __restrict__ out, float* __restrict__ auxs) {
  const int lane = threadIdx.x;           // = local row
  const int bid  = blockIdx.x;            // rowtile
  const int row_g = bid * 64 + lane;

  float c[32];
  #pragma unroll
  for (int g = 0; g < 8; ++g) {
    float4 a = make_float4(0.f, 0.f, 0.f, 0.f);
    #pragma unroll
    for (int s = 0; s < NS; ++s) {
      float4 p = *(const float4*)(pbase + (size_t)(s * 256 + bid) * 2048 + lane * 32 + g * 4);
      a.x += p.x; a.y += p.y; a.z += p.z; a.w += p.w;
    }
    c[g * 4 + 0] = a.x; c[g * 4 + 1] = a.y; c[g * 4 + 2] = a.z; c[g * 4 + 3] = a.w;
  }

  float brv[16], bnv[16], ev[16];
  #pragma unroll
  for (int g = 0; g < 4; ++g) {
    *(float4*)(brv + g * 4) = *(const float4*)(br + g * 4);
    *(float4*)(bnv + g * 4) = *(const float4*)(bn + g * 4);
    *(float4*)(ev  + g * 4) = *(const float4*)(eps + (size_t)row_g * NEXP + g * 4);
  }

  float s[16];
  #pragma unroll
  for (int e = 0; e < 16; ++e) {
    float lg = c[e] + brv[e];
    float nz = c[16 + e] + bnv[e];
    float sp = fmaxf(nz, 0.f) + log1pf(expf(-fabsf(nz)));  // stable softplus
    s[e] = lg + ev[e] * sp;                                 // TEMPERATURE == 1
  }

  // top-2 (ties -> lowest index, matching lax.top_k)
  float b1 = s[0]; int i1 = 0;
  #pragma unroll
  for (int e = 1; e < 16; ++e) { if (s[e] > b1) { b1 = s[e]; i1 = e; } }
  float b2 = -INFINITY; int i2 = 0;
  #pragma unroll
  for (int e = 0; e < 16; ++e) { if (e != i1 && s[e] > b2) { b2 = s[e]; i2 = e; } }

  float t2 = expf(b2 - b1);
  float p1 = 1.f / (1.f + t2);
  float p2 = t2 / (1.f + t2);

  float v[16];
  #pragma unroll
  for (int e = 0; e < 16; ++e)
    v[e] = (e == i1) ? p1 : ((e == i2) ? p2 : 0.f);

  float* orow = out + (size_t)row_g * NEXP;
  *(float4*)(orow + 0)  = make_float4(v[0], v[1], v[2], v[3]);
  *(float4*)(orow + 4)  = make_float4(v[4], v[5], v[6], v[7]);
  *(float4*)(orow + 8)  = make_float4(v[8], v[9], v[10], v[11]);
  *(float4*)(orow + 12) = make_float4(v[12], v[13], v[14], v[15]);

  float* oidx = out + IDX_OFF + (size_t)row_g * 2;
  *(float2*)oidx = make_float2((float)i1, (float)i2);

  // per-rowtile expert-prob sums over 64 rows (full-wave butterfly)
  #pragma unroll
  for (int m = 1; m < 64; m <<= 1) {
    #pragma unroll
    for (int e = 0; e < 16; ++e) v[e] += __shfl_xor(v[e], m, 64);
  }
  if (lane == 0) {
    float* ap = auxs + (size_t)bid * 16;
    *(float4*)(ap + 0)  = make_float4(v[0], v[1], v[2], v[3]);
    *(float4*)(ap + 4)  = make_float4(v[4], v[5], v[6], v[7]);
    *(float4*)(ap + 8)  = make_float4(v[8], v[9], v[10], v[11]);
    *(float4*)(ap + 12) = make_float4(v[12], v[13], v[14], v[15]);
  }
}

__global__ void router_aux_k(const float* __restrict__ auxs, float* __restrict__ out_aux) {
  __shared__ float red[16][17];
  __shared__ float sq[16];
  const int t = threadIdx.x;
  const int e = t & 15;
  const int g = t >> 4;
  float ssum = 0.f;
  #pragma unroll
  for (int b = 0; b < 16; ++b) ssum += auxs[(size_t)(g * 16 + b) * 16 + e];
  red[g][e] = ssum;
  __syncthreads();
  if (t < 16) {
    float tot = 0.f;
    #pragma unroll
    for (int gg = 0; gg < 16; ++gg) tot += red[gg][t];
    float diff = tot * (1.f / 16384.f) - 0.0625f;
    sq[t] = diff * diff;
  }
  __syncthreads();
  if (t == 0) {
    float a = 0.f;
    #pragma unroll
    for (int i = 0; i < 16; ++i) a += sq[i];
    *out_aux = a;
  }
}

extern "C" void kernel_launch(void* const* d_in, const int* in_sizes, int n_in,
                              void* d_out, int out_size, void* d_ws, size_t ws_size,
                              hipStream_t stream) {
  const float* x   = (const float*)d_in[0];
  const float* wr  = (const float*)d_in[1];
  const float* br  = (const float*)d_in[2];
  const float* wn  = (const float*)d_in[3];
  const float* bn  = (const float*)d_in[4];
  const float* eps = (const float*)d_in[5];
  float* out = (float*)d_out;

  float* wsf   = (float*)d_ws;
  float* auxs  = wsf;            // 256*16 floats
  float* pbase = wsf + 4096;     // NS*256*2048 floats

  const size_t need4 = (size_t)(4096 + 4 * 524288) * 4;
  const size_t need2 = (size_t)(4096 + 2 * 524288) * 4;

  if (ws_size >= need4) {
    gemv_k<4><<<1024, 256, 0, stream>>>(x, wr, wn, pbase);
    epi_k<4><<<256, 64, 0, stream>>>(pbase, br, bn, eps, out, auxs);
  } else if (ws_size >= need2) {
    gemv_k<2><<<512, 256, 0, stream>>>(x, wr, wn, pbase);
    epi_k<2><<<256, 64, 0, stream>>>(pbase, br, bn, eps, out, auxs);
  } else {
    gemv_k<1><<<256, 256, 0, stream>>>(x, wr, wn, pbase);
    epi_k<1><<<256, 64, 0, stream>>>(pbase, br, bn, eps, out, auxs);
  }
  router_aux_k<<<1, 256, 0, stream>>>(auxs, out + AUX_OFF);
}